// Round 3
// baseline (1053.810 us; speedup 1.0000x reference)
//
#include <hip/hip_runtime.h>

typedef unsigned short u16;
typedef unsigned int u32;
typedef __bf16 bf16x8 __attribute__((ext_vector_type(8)));
typedef float f32x4 __attribute__((ext_vector_type(4)));

#define MFMA16(a, b, c) __builtin_amdgcn_mfma_f32_16x16x32_bf16((a), (b), (c), 0, 0, 0)

// ---- constants ----
#define S_LEN 2048
#define D_HEAD 128
#define NHEADS 16
#define NBH 32          // B*HEADS
#define QDIM 2048
#define NPROJ 22528     // 3*INNER + 2*MLP_HID
#define NCAT 10240      // INNER + MLP_HID
#define MROWS 4096      // B*S

#define BARRIER() __builtin_amdgcn_s_barrier()
#define SCHEDB() __builtin_amdgcn_sched_barrier(0)
#define WAITLGKM() asm volatile("s_waitcnt lgkmcnt(0)" ::: "memory")
#define WAITVM8() asm volatile("s_waitcnt vmcnt(8)" ::: "memory")
#define WAITVM4() asm volatile("s_waitcnt vmcnt(4)" ::: "memory")
#define WAITVM0() asm volatile("s_waitcnt vmcnt(0)" ::: "memory")

__device__ __forceinline__ float bf2f(u16 u) { return __uint_as_float(((u32)u) << 16); }
__device__ __forceinline__ u16 f2bf(float f) {
  u32 u = __float_as_uint(f);
  return (u16)((u + 0x7FFFu + ((u >> 16) & 1u)) >> 16);
}
__device__ __forceinline__ void gld16(const void* g, void* l) {
  __builtin_amdgcn_global_load_lds((__attribute__((address_space(1))) void*)(g),
                                   (__attribute__((address_space(3))) void*)(l), 16, 0, 0);
}

// ---------------- f32 -> bf16 elementwise (vectorized) ----------------
__global__ __launch_bounds__(256) void f32_to_bf16(const float* __restrict__ in,
                                                   u16* __restrict__ out) {
  const u32 i = blockIdx.x * 256 + threadIdx.x;  // one float4 per thread
  const float4 v = ((const float4*)in)[i];
  uint2 o;
  o.x = (u32)f2bf(v.x) | ((u32)f2bf(v.y) << 16);
  o.y = (u32)f2bf(v.z) | ((u32)f2bf(v.w) << 16);
  ((uint2*)out)[i] = o;
}

// ---------------- tiled transpose-convert: in[R][C] f32 -> out[C][R] bf16 ----------------
__global__ __launch_bounds__(256) void transpose_f32_bf16(const float* __restrict__ in,
                                                          u16* __restrict__ out, int R, int C) {
  __shared__ u16 tile[64][65];
  const int tx = threadIdx.x & 63;
  const int ty = threadIdx.x >> 6;
  const int c0 = blockIdx.x * 64;
  const int r0 = blockIdx.y * 64;
#pragma unroll
  for (int it = 0; it < 16; ++it) {
    const int rr = ty * 16 + it;
    tile[rr][tx] = f2bf(in[(size_t)(r0 + rr) * C + c0 + tx]);
  }
  __syncthreads();
#pragma unroll
  for (int it = 0; it < 16; ++it) {
    const int rr = ty * 16 + it;
    out[(size_t)(c0 + rr) * R + r0 + tx] = tile[tx][rr];
  }
}

// ---------------- batched bf16 transpose: in[z][R][C] -> out[z][C][R] ----------------
__global__ __launch_bounds__(256) void transpose_bf16_b(const u16* __restrict__ in,
                                                        u16* __restrict__ out, int R, int C) {
  __shared__ u16 tile[64][65];
  const int z = blockIdx.z;
  in += (size_t)z * R * C;
  out += (size_t)z * R * C;
  const int tx = threadIdx.x & 63;
  const int ty = threadIdx.x >> 6;
  const int c0 = blockIdx.x * 64;
  const int r0 = blockIdx.y * 64;
#pragma unroll
  for (int it = 0; it < 16; ++it) {
    const int rr = ty * 16 + it;
    tile[rr][tx] = in[(size_t)(r0 + rr) * C + c0 + tx];
  }
  __syncthreads();
#pragma unroll
  for (int it = 0; it < 16; ++it) {
    const int rr = ty * 16 + it;
    out[(size_t)(c0 + rr) * R + r0 + tx] = tile[tx][rr];
  }
}

// ============ 256x256 pipelined bf16 GEMM v2 ============
// C[M][N] = A[M][K] * Bt[N][K]^T, bf16 out. 512 thr = 8 waves (2M x 4N),
// per-wave 128x64 out, BK=64, dbuf LDS 128 KB.
//
// K-loop = 4 MFMA clusters (16 MFMA each), cluster order Mh0k0,Mh1k0,Mh0k1,Mh1k1.
// EVERY ds_read is issued one cluster ahead of its consumer (compiler inserts
// counted lgkmcnt). Only TWO barriers per K-tile:
//   S2-end: lgkm0+barrier  -> all B-reads retired -> stage-B@S3 WAR-safe
//   S3-end: lgkm0+vmcnt(4)+barrier -> A-reads retired (stage-A@S4 WAR-safe)
//           AND kt+1's staged data globally visible (per-wave vmcnt before
//           barrier => cross-wave visibility)
// Staging: B(kt+2)@S3, A(kt+2)@S4; vmcnt(4) keeps kt+2's B in flight.
// Register ping-pong is fully static (rule #20): aA/aB, bA/bB.

__device__ __forceinline__ void stage_tile(const u16* __restrict__ src, int ldk,
                                           u16* ldsbase, int k0, int t) {
  const int w64 = t & ~63;  // w*64
#pragma unroll
  for (int j = 0; j < 4; ++j) {
    const int o = (j * 512 + t) * 16;       // byte offset in 32KB tile
    const int row = o >> 7;                 // 128B per row
    const int g = (o & 127) >> 4;
    const int gs = g ^ (row & 7);           // pre-swizzle the SOURCE
    gld16(src + (size_t)row * ldk + k0 + gs * 8, ldsbase + (((j * 512 + w64) * 16) >> 1));
  }
}

__device__ __forceinline__ bf16x8 rdfrag(const u16* lds, int row, int kc, int lg) {
  return *(const bf16x8*)&lds[row * 64 + (((kc * 4 + lg) ^ (row & 7)) << 3)];
}

#define CLUSTER(AR, AF, BF)                                            \
  __builtin_amdgcn_s_setprio(1);                                       \
  _Pragma("unroll") for (int i = 0; i < 4; ++i)                        \
  _Pragma("unroll") for (int j = 0; j < 4; ++j)                        \
      acc[(AR) + i][j] = MFMA16(AF[i], BF[j], acc[(AR) + i][j]);       \
  __builtin_amdgcn_s_setprio(0);                                       \
  SCHEDB();

__global__ __launch_bounds__(512, 2) void gemm256(const u16* __restrict__ A,
                                                  const u16* __restrict__ Bt,
                                                  u16* __restrict__ C, int N, int K,
                                                  int nbm) {
  __shared__ u16 As[2][256 * 64];
  __shared__ u16 Bs[2][256 * 64];
  const int t = threadIdx.x;
  const int l = t & 63;
  const int w = t >> 6;
  const int lr = l & 15;
  const int lg = l >> 4;
  const int wm = (w >> 2) * 128;
  const int wn = (w & 3) * 64;

  // XCD swizzle: contiguous chunk per XCD; column-major (bm fastest) so each
  // XCD owns full B-columns -> B fetched ~once per XCD.
  const int nwg = gridDim.x;
  const int cpx = nwg >> 3;
  const int swz = (blockIdx.x & 7) * cpx + (blockIdx.x >> 3);
  const int bm = swz % nbm;
  const int bn = swz / nbm;
  const u16* Ab = A + (size_t)(bm * 256) * K;
  const u16* Bb = Bt + (size_t)(bn * 256) * K;
  const int NT = K >> 6;

  f32x4 acc[8][4] = {};
  bf16x8 aA[4], aB[4], bA[4], bB[4];

  // prologue: stage K-tiles 0 and 1 (16 loads/thread: oldest 8 = tile 0)
  stage_tile(Bb, K, &Bs[0][0], 0, t);
  stage_tile(Ab, K, &As[0][0], 0, t);
  stage_tile(Bb, K, &Bs[1][0], 64, t);
  stage_tile(Ab, K, &As[1][0], 64, t);
  WAITVM8();  // K0 landed; K1 in flight
  BARRIER();
  // preload c1 operands of kt=0: aA = Mh0k0, bA = k0
#pragma unroll
  for (int i = 0; i < 4; ++i) aA[i] = rdfrag(&As[0][0], wm + i * 16 + lr, 0, lg);
#pragma unroll
  for (int j = 0; j < 4; ++j) bA[j] = rdfrag(&Bs[0][0], wn + j * 16 + lr, 0, lg);

  for (int kt = 0; kt < NT; ++kt) {
    const int d = kt & 1;
    const u16* Al = &As[d][0];
    const u16* Bl = &Bs[d][0];
    const u16* An = &As[d ^ 1][0];
    const u16* Bn = &Bs[d ^ 1][0];
    const bool pre = (kt + 2 < NT);

    // ---- S1: read aMh1k0 -> aB (for c2); MFMA c1 = Mh0 x k0 (aA x bA)
#pragma unroll
    for (int i = 0; i < 4; ++i) aB[i] = rdfrag(Al, wm + 64 + i * 16 + lr, 0, lg);
    CLUSTER(0, aA, bA)

    // ---- S2: read aMh0k1 -> aA, b_k1 -> bB (for c3); MFMA c2 = Mh1 x k0 (aB x bA)
#pragma unroll
    for (int i = 0; i < 4; ++i) aA[i] = rdfrag(Al, wm + i * 16 + lr, 1, lg);
#pragma unroll
    for (int j = 0; j < 4; ++j) bB[j] = rdfrag(Bl, wn + j * 16 + lr, 1, lg);
    CLUSTER(4, aB, bA)
    WAITLGKM();   // all this wave's B-reads (and A) retired
    BARRIER();    // => every wave's reads of B-region retired: stage-B is WAR-safe

    // ---- S3: stage B(kt+2); read aMh1k1 -> aB (for c4); MFMA c3 = Mh0 x k1 (aA x bB)
    if (pre) stage_tile(Bb, K, &Bs[d][0], (kt + 2) * 64, t);
#pragma unroll
    for (int i = 0; i < 4; ++i) aB[i] = rdfrag(Al, wm + 64 + i * 16 + lr, 1, lg);
    CLUSTER(0, aA, bB)
    WAITLGKM();   // this wave's A-reads retired (stage-A WAR)
    if (pre) {
      WAITVM4();  // drain kt+1's 8 loads; keep kt+2's B (4) in flight
    } else {
      WAITVM0();
    }
    BARRIER();    // kt+1's tile now globally visible; A-region WAR-safe

    // ---- S4: stage A(kt+2); lookahead reads for kt+1's c1 (aA=Mh0k0', bA=k0');
    //          MFMA c4 = Mh1 x k1 (aB x bB)
    if (pre) stage_tile(Ab, K, &As[d][0], (kt + 2) * 64, t);
    if (kt + 1 < NT) {
#pragma unroll
      for (int i = 0; i < 4; ++i) aA[i] = rdfrag(An, wm + i * 16 + lr, 0, lg);
#pragma unroll
      for (int j = 0; j < 4; ++j) bA[j] = rdfrag(Bn, wn + j * 16 + lr, 0, lg);
    }
    CLUSTER(4, aB, bB)
  }

  // epilogue: bf16 store
  const int m0 = bm * 256 + wm;
  const int n0 = bn * 256 + wn;
#pragma unroll
  for (int i = 0; i < 8; ++i)
#pragma unroll
    for (int j = 0; j < 4; ++j)
#pragma unroll
      for (int r = 0; r < 4; ++r) {
        const int row = m0 + i * 16 + lg * 4 + r;
        const int col = n0 + j * 16 + lr;
        C[(size_t)row * N + col] = f2bf(acc[i][j][r]);
      }
}

// ---------------- 128x128 bf16 GEMM (m97 structure) — used for GEMM2 ----------------
// 1-D grid with XCD swizzle, row-major chunks (each XCD owns bm-rows -> A once).
template <int OUTF32>
__global__ __launch_bounds__(256, 2) void gemm_bt(const u16* __restrict__ A,
                                                  const u16* __restrict__ Bt,
                                                  void* __restrict__ Cvoid,
                                                  const float* __restrict__ bias, int N, int K,
                                                  int nbn) {
  __shared__ u16 As[128 * 64];
  __shared__ u16 Bs[128 * 64];
  const int t = threadIdx.x;
  const int l = t & 63;
  const int w = t >> 6;
  const int lr = l & 15;
  const int lg = l >> 4;
  const int nwg = gridDim.x;
  const int cpx = nwg >> 3;
  const int swz = (blockIdx.x & 7) * cpx + (blockIdx.x >> 3);
  const int bm = swz / nbn;
  const int bn = swz % nbn;
  const int m0 = bm * 128;
  const int n0 = bn * 128;
  const int wm = (w >> 1) * 64;
  const int wn = (w & 1) * 64;

  f32x4 acc[4][4] = {};
  const int obase = w * 1024 + l * 16;  // byte offset within 16KB tile

  for (int k0 = 0; k0 < K; k0 += 64) {
#pragma unroll
    for (int rnd = 0; rnd < 4; ++rnd) {
      const int o = obase + rnd * 4096;
      const int row = o >> 7;          // 128 B per row
      const int g = (o & 127) >> 4;    // 16B granule within row
      const int gs = g ^ (row & 7);    // pre-swizzle the SOURCE
      gld16(A + (size_t)(m0 + row) * K + k0 + gs * 8, &As[rnd * 2048 + w * 512]);
      gld16(Bt + (size_t)(n0 + row) * K + k0 + gs * 8, &Bs[rnd * 2048 + w * 512]);
    }
    __syncthreads();

    bf16x8 af[4][2], bfr[4][2];
#pragma unroll
    for (int i = 0; i < 4; ++i) {
#pragma unroll
      for (int kc = 0; kc < 2; ++kc) {
        const int ra = wm + i * 16 + lr;
        af[i][kc] = *(const bf16x8*)&As[ra * 64 + (((kc * 4 + lg) ^ (ra & 7)) * 8)];
        const int rb = wn + i * 16 + lr;
        bfr[i][kc] = *(const bf16x8*)&Bs[rb * 64 + (((kc * 4 + lg) ^ (rb & 7)) * 8)];
      }
    }
#pragma unroll
    for (int kc = 0; kc < 2; ++kc)
#pragma unroll
      for (int i = 0; i < 4; ++i)
#pragma unroll
        for (int j = 0; j < 4; ++j)
          acc[i][j] = MFMA16(af[i][kc], bfr[j][kc], acc[i][j]);
    __syncthreads();
  }

  if (OUTF32) {
    float* C = (float*)Cvoid;
#pragma unroll
    for (int i = 0; i < 4; ++i)
#pragma unroll
      for (int j = 0; j < 4; ++j)
#pragma unroll
        for (int r = 0; r < 4; ++r) {
          const int row = m0 + wm + i * 16 + lg * 4 + r;
          const int col = n0 + wn + j * 16 + lr;
          C[(size_t)row * N + col] = acc[i][j][r] + bias[col];
        }
  } else {
    u16* C = (u16*)Cvoid;
#pragma unroll
    for (int i = 0; i < 4; ++i)
#pragma unroll
      for (int j = 0; j < 4; ++j)
#pragma unroll
        for (int r = 0; r < 4; ++r) {
          const int row = m0 + wm + i * 16 + lg * 4 + r;
          const int col = n0 + wn + j * 16 + lr;
          C[(size_t)row * N + col] = f2bf(acc[i][j][r]);
        }
  }
}

// ---------------- fused RMSNorm + RoPE + split to Q/K/V [bh][s][d] ----------------
__global__ __launch_bounds__(256) void norm_rope(const u16* __restrict__ proj,
                                                 const float* __restrict__ cosT,
                                                 const float* __restrict__ sinT,
                                                 const float* __restrict__ wq,
                                                 const float* __restrict__ wk,
                                                 u16* __restrict__ Qb, u16* __restrict__ Kb,
                                                 u16* __restrict__ Vb) {
  const int l = threadIdx.x & 63;
  const int wg = blockIdx.x * 4 + (threadIdx.x >> 6);
  const int h = wg & 15;
  const int r = wg >> 4;       // 0..4095
  const int b = r >> 11;       // /S
  const int s = r & 2047;
  const int bh = (b << 4) + h;

  const u16* p = proj + (size_t)r * NPROJ + h * 128 + 2 * l;
  const u32 qu = *(const u32*)(p);
  const u32 ku = *(const u32*)(p + QDIM);
  const u32 vu = *(const u32*)(p + 2 * QDIM);

  const float q0 = bf2f(qu & 0xffff), q1 = bf2f(qu >> 16);
  const float k0 = bf2f(ku & 0xffff), k1 = bf2f(ku >> 16);

  float sq = q0 * q0 + q1 * q1;
  float sk = k0 * k0 + k1 * k1;
#pragma unroll
  for (int m = 1; m < 64; m <<= 1) {
    sq += __shfl_xor(sq, m);
    sk += __shfl_xor(sk, m);
  }
  const float scq = rsqrtf(sq * (1.0f / 128.0f) + 1e-5f);
  const float sck = rsqrtf(sk * (1.0f / 128.0f) + 1e-5f);

  const float2 cc = *(const float2*)&cosT[s * 128 + 2 * l];
  const float2 ssn = *(const float2*)&sinT[s * 128 + 2 * l];
  const float w0 = wq[2 * l], w1 = wq[2 * l + 1];
  const float x0 = wk[2 * l], x1 = wk[2 * l + 1];

  const float qn0 = q0 * scq * w0, qn1 = q1 * scq * w1;
  const float kn0 = k0 * sck * x0, kn1 = k1 * sck * x1;

  const float ATT = 0.08838834764831845f;  // 128^-0.5 (pre-scale Q for attention)
  const float qr0 = (qn0 * cc.x - qn1 * ssn.x) * ATT;
  const float qr1 = (qn1 * cc.y + qn0 * ssn.y) * ATT;
  const float kr0 = kn0 * cc.x - kn1 * ssn.x;
  const float kr1 = kn1 * cc.y + kn0 * ssn.y;

  const size_t dst = ((size_t)bh * S_LEN + s) * 128 + 2 * l;
  *(u32*)(Qb + dst) = (u32)f2bf(qr0) | ((u32)f2bf(qr1) << 16);
  *(u32*)(Kb + dst) = (u32)f2bf(kr0) | ((u32)f2bf(kr1) << 16);
  *(u32*)(Vb + dst) = vu;  // plain copy (bf16 passthrough)
}

// ---------------- SwiGLU: silu(m1)*m2 -> Cat[:, 2048:10240] ----------------
__global__ __launch_bounds__(256) void swiglu(const u16* __restrict__ proj,
                                              u16* __restrict__ Cat) {
  const u32 i = blockIdx.x * 256 + threadIdx.x;  // quad index
  const u32 r = i >> 11;
  const u32 c = (i & 2047) * 4;
  const u16* p1 = proj + (size_t)r * NPROJ + 3 * QDIM + c;
  const uint2 a = *(const uint2*)p1;
  const uint2 bv = *(const uint2*)(p1 + 8192);
  const float a0 = bf2f(a.x & 0xffff), a1 = bf2f(a.x >> 16);
  const float a2 = bf2f(a.y & 0xffff), a3 = bf2f(a.y >> 16);
  const float b0 = bf2f(bv.x & 0xffff), b1 = bf2f(bv.x >> 16);
  const float b2 = bf2f(bv.y & 0xffff), b3 = bf2f(bv.y >> 16);
  const float o0 = a0 / (1.f + __expf(-a0)) * b0;
  const float o1 = a1 / (1.f + __expf(-a1)) * b1;
  const float o2 = a2 / (1.f + __expf(-a2)) * b2;
  const float o3 = a3 / (1.f + __expf(-a3)) * b3;
  uint2 o;
  o.x = (u32)f2bf(o0) | ((u32)f2bf(o1) << 16);
  o.y = (u32)f2bf(o2) | ((u32)f2bf(o3) << 16);
  *(uint2*)(Cat + (size_t)r * NCAT + QDIM + c) = o;
}

// ---------------- flash attention: 4 waves x 32 q-rows, KV tile = 64 ----------------
__global__ __launch_bounds__(256, 2) void attn_fwd(const u16* __restrict__ Qb,
                                                   const u16* __restrict__ Kb,
                                                   const u16* __restrict__ Vt,
                                                   u16* __restrict__ Cat) {
  __shared__ u16 Ks[64 * 128];   // [key][d], swz g^=key&7 (16 granules/row)
  __shared__ u16 Vs[128 * 64];   // [d][key], swz g^=d&7 (8 granules/row)
  __shared__ u16 Ps[4][32 * 64]; // per-wave P [q][key], swz g^=q&7

  const int t = threadIdx.x;
  const int l = t & 63;
  const int w = t >> 6;
  const int lr = l & 15;
  const int lg = l >> 4;
  const int qt = blockIdx.x;
  const int bh = blockIdx.y;
  const int b = bh >> 4;
  const int h = bh & 15;
  const int q0 = qt * 128 + w * 32;

  bf16x8 qf[2][4];
#pragma unroll
  for (int im = 0; im < 2; ++im)
#pragma unroll
    for (int kc = 0; kc < 4; ++kc)
      qf[im][kc] =
          *(const bf16x8*)&Qb[((size_t)bh * S_LEN + q0 + im * 16 + lr) * 128 + kc * 32 + lg * 8];

  f32x4 oacc[2][8] = {};
  float mrun[2][4], lrun[2][4];
#pragma unroll
  for (int im = 0; im < 2; ++im)
#pragma unroll
    for (int r = 0; r < 4; ++r) {
      mrun[im][r] = -1e30f;
      lrun[im][r] = 0.f;
    }

  const int obase = w * 1024 + l * 16;
  u16* P = Ps[w];

  for (int kt = 0; kt < 32; ++kt) {
    const int kk0 = kt * 64;
#pragma unroll
    for (int rnd = 0; rnd < 4; ++rnd) {
      const int o = obase + rnd * 4096;
      {
        const int key = o >> 8;
        const int g = (o & 255) >> 4;
        const int gs = g ^ (key & 7);
        gld16(Kb + ((size_t)bh * S_LEN + kk0 + key) * 128 + gs * 8, &Ks[rnd * 2048 + w * 512]);
      }
      {
        const int d = o >> 7;
        const int g = (o & 127) >> 4;
        const int gs = g ^ (d & 7);
        gld16(Vt + ((size_t)bh * 128 + d) * S_LEN + kk0 + gs * 8, &Vs[rnd * 2048 + w * 512]);
      }
    }
    __syncthreads();

    // QK^T
    f32x4 sf[2][4] = {};
#pragma unroll
    for (int j = 0; j < 4; ++j) {
      const int kr = j * 16 + lr;
      bf16x8 kf[4];
#pragma unroll
      for (int kc = 0; kc < 4; ++kc)
        kf[kc] = *(const bf16x8*)&Ks[kr * 128 + (((kc * 4 + lg) ^ (kr & 7)) * 8)];
#pragma unroll
      for (int kc = 0; kc < 4; ++kc)
#pragma unroll
        for (int im = 0; im < 2; ++im)
          sf[im][j] = MFMA16(qf[im][kc], kf[kc], sf[im][j]);
    }

    // online softmax
#pragma unroll
    for (int im = 0; im < 2; ++im) {
#pragma unroll
      for (int r = 0; r < 4; ++r) {
        float v = fmaxf(fmaxf(sf[im][0][r], sf[im][1][r]), fmaxf(sf[im][2][r], sf[im][3][r]));
        v = fmaxf(v, __shfl_xor(v, 1));
        v = fmaxf(v, __shfl_xor(v, 2));
        v = fmaxf(v, __shfl_xor(v, 4));
        v = fmaxf(v, __shfl_xor(v, 8));
        const float mnew = fmaxf(mrun[im][r], v);
        const float alpha = __expf(mrun[im][r] - mnew);
        mrun[im][r] = mnew;
        float psum = 0.f;
#pragma unroll
        for (int j = 0; j < 4; ++j) {
          const float pv = __expf(sf[im][j][r] - mnew);
          sf[im][j][r] = pv;
          psum += pv;
        }
        psum += __shfl_xor(psum, 1);
        psum += __shfl_xor(psum, 2);
        psum += __shfl_xor(psum, 4);
        psum += __shfl_xor(psum, 8);
        lrun[im][r] = lrun[im][r] * alpha + psum;
#pragma unroll
        for (int df = 0; df < 8; ++df) oacc[im][df][r] *= alpha;
      }
    }

    // P -> per-wave LDS (swizzled for the A-frag read)
#pragma unroll
    for (int im = 0; im < 2; ++im)
#pragma unroll
      for (int j = 0; j < 4; ++j)
#pragma unroll
        for (int r = 0; r < 4; ++r) {
          const int q = im * 16 + lg * 4 + r;
          const int key = j * 16 + lr;
          const int g = key >> 3;
          P[q * 64 + ((g ^ (q & 7)) * 8) + (key & 7)] = f2bf(sf[im][j][r]);
        }

    // PV
#pragma unroll
    for (int kc = 0; kc < 2; ++kc) {
      bf16x8 pa[2];
#pragma unroll
      for (int im = 0; im < 2; ++im) {
        const int q = im * 16 + lr;
        pa[im] = *(const bf16x8*)&P[q * 64 + (((kc * 4 + lg) ^ (q & 7)) * 8)];
      }
#pragma unroll
      for (int df = 0; df < 8; ++df) {
        const int d = df * 16 + lr;
        const bf16x8 vb = *(const bf16x8*)&Vs[d * 64 + (((kc * 4 + lg) ^ (d & 7)) * 8)];
#pragma unroll
        for (int im = 0; im < 2; ++im) oacc[im][df] = MFMA16(pa[im], vb, oacc[im][df]);
      }
    }
    __syncthreads();
  }

  // epilogue
#pragma unroll
  for (int im = 0; im < 2; ++im)
#pragma unroll
    for (int r = 0; r < 4; ++r) {
      const float inv = 1.0f / lrun[im][r];
      const int row = b * S_LEN + q0 + im * 16 + lg * 4 + r;
#pragma unroll
      for (int df = 0; df < 8; ++df) {
        const int col = h * 128 + df * 16 + lr;
        Cat[(size_t)row * NCAT + col] = f2bf(oacc[im][df][r] * inv);
      }
    }
}

// ---------------- launch ----------------
extern "C" void kernel_launch(void* const* d_in, const int* in_sizes, int n_in, void* d_out,
                              int out_size, void* d_ws, size_t ws_size, hipStream_t stream) {
  (void)in_sizes; (void)n_in; (void)out_size; (void)ws_size;
  const float* hs = (const float*)d_in[0];
  const float* rcos = (const float*)d_in[1];
  const float* rsin = (const float*)d_in[2];
  const float* Wqkv = (const float*)d_in[3];
  const float* wq = (const float*)d_in[4];
  const float* wk = (const float*)d_in[5];
  const float* Wout = (const float*)d_in[6];
  const float* bout = (const float*)d_in[7];
  float* out = (float*)d_out;

  char* ws = (char*)d_ws;
  size_t off = 0;
  auto nxt = [&](size_t bytes) {
    char* p = ws + off;
    off += (bytes + 255) & ~(size_t)255;
    return p;
  };
  u16* Xb = (u16*)nxt((size_t)MROWS * QDIM * 2);
  u16* Wqkvt = (u16*)nxt((size_t)NPROJ * QDIM * 2);
  u16* Woutt = (u16*)nxt((size_t)QDIM * NCAT * 2);
  u16* proj = (u16*)nxt((size_t)MROWS * NPROJ * 2);
  u16* Qb = (u16*)nxt((size_t)NBH * S_LEN * D_HEAD * 2);
  u16* Kb = (u16*)nxt((size_t)NBH * S_LEN * D_HEAD * 2);
  u16* Vb = (u16*)nxt((size_t)NBH * S_LEN * D_HEAD * 2);
  u16* Vt = (u16*)nxt((size_t)NBH * S_LEN * D_HEAD * 2);
  u16* Cat = (u16*)nxt((size_t)MROWS * NCAT * 2);

  // 1) convert / transpose to bf16
  f32_to_bf16<<<(MROWS * QDIM / 4) / 256, 256, 0, stream>>>(hs, Xb);
  transpose_f32_bf16<<<dim3(NPROJ / 64, QDIM / 64), 256, 0, stream>>>(Wqkv, Wqkvt, QDIM, NPROJ);
  transpose_f32_bf16<<<dim3(QDIM / 64, NCAT / 64), 256, 0, stream>>>(Wout, Woutt, NCAT, QDIM);

  // 2) fused QKV+MLP projection — 256² pipelined v2, grid 16x88=1408 (div by 8)
  gemm256<<<(MROWS / 256) * (NPROJ / 256), 512, 0, stream>>>(Xb, Wqkvt, proj, NPROJ, QDIM,
                                                             MROWS / 256);

  // 3) RMSNorm + RoPE + QKV split; V transpose
  norm_rope<<<MROWS * NHEADS / 4, 256, 0, stream>>>(proj, rcos, rsin, wq, wk, Qb, Kb, Vb);
  transpose_bf16_b<<<dim3(D_HEAD / 64, S_LEN / 64, NBH), 256, 0, stream>>>(Vb, Vt, S_LEN, D_HEAD);

  // 4) SwiGLU
  swiglu<<<(MROWS * 8192 / 4) / 256, 256, 0, stream>>>(proj, Cat);

  // 5) flash attention
  attn_fwd<<<dim3(S_LEN / 128, NBH), 256, 0, stream>>>(Qb, Kb, Vt, Cat);

  // 6) output projection + bias — 128² with XCD swizzle, grid 512 (div by 8)
  gemm_bt<1><<<(MROWS / 128) * (QDIM / 128), 256, 0, stream>>>(Cat, Woutt, out, bout, QDIM,
                                                               NCAT, QDIM / 128);
}

// Round 4
// 933.678 us; speedup vs baseline: 1.1287x; 1.1287x over previous
//
#include <hip/hip_runtime.h>

typedef unsigned short u16;
typedef unsigned int u32;
typedef __bf16 bf16x8 __attribute__((ext_vector_type(8)));
typedef float f32x4 __attribute__((ext_vector_type(4)));

#define MFMA16(a, b, c) __builtin_amdgcn_mfma_f32_16x16x32_bf16((a), (b), (c), 0, 0, 0)

// ---- constants ----
#define S_LEN 2048
#define D_HEAD 128
#define NHEADS 16
#define NBH 32          // B*HEADS
#define QDIM 2048
#define NPROJ 22528     // 3*INNER + 2*MLP_HID
#define NCAT 10240      // INNER + MLP_HID
#define MROWS 4096      // B*S

#define BARRIER() __builtin_amdgcn_s_barrier()
#define WAITVM0() asm volatile("s_waitcnt vmcnt(0)" ::: "memory")

__device__ __forceinline__ float bf2f(u16 u) { return __uint_as_float(((u32)u) << 16); }
__device__ __forceinline__ u16 f2bf(float f) {
  u32 u = __float_as_uint(f);
  return (u16)((u + 0x7FFFu + ((u >> 16) & 1u)) >> 16);
}
__device__ __forceinline__ void gld16(const void* g, void* l) {
  __builtin_amdgcn_global_load_lds((__attribute__((address_space(1))) void*)(g),
                                   (__attribute__((address_space(3))) void*)(l), 16, 0, 0);
}

// ---------------- f32 -> bf16 elementwise (vectorized) ----------------
__global__ __launch_bounds__(256) void f32_to_bf16(const float* __restrict__ in,
                                                   u16* __restrict__ out) {
  const u32 i = blockIdx.x * 256 + threadIdx.x;  // one float4 per thread
  const float4 v = ((const float4*)in)[i];
  uint2 o;
  o.x = (u32)f2bf(v.x) | ((u32)f2bf(v.y) << 16);
  o.y = (u32)f2bf(v.z) | ((u32)f2bf(v.w) << 16);
  ((uint2*)out)[i] = o;
}

// ---------------- tiled transpose-convert: in[R][C] f32 -> out[C][R] bf16 ----------------
__global__ __launch_bounds__(256) void transpose_f32_bf16(const float* __restrict__ in,
                                                          u16* __restrict__ out, int R, int C) {
  __shared__ u16 tile[64][65];
  const int tx = threadIdx.x & 63;
  const int ty = threadIdx.x >> 6;
  const int c0 = blockIdx.x * 64;
  const int r0 = blockIdx.y * 64;
#pragma unroll
  for (int it = 0; it < 16; ++it) {
    const int rr = ty * 16 + it;
    tile[rr][tx] = f2bf(in[(size_t)(r0 + rr) * C + c0 + tx]);
  }
  __syncthreads();
#pragma unroll
  for (int it = 0; it < 16; ++it) {
    const int rr = ty * 16 + it;
    out[(size_t)(c0 + rr) * R + r0 + tx] = tile[tx][rr];
  }
}

// ---------------- batched bf16 transpose: in[z][R][C] -> out[z][C][R] ----------------
__global__ __launch_bounds__(256) void transpose_bf16_b(const u16* __restrict__ in,
                                                        u16* __restrict__ out, int R, int C) {
  __shared__ u16 tile[64][65];
  const int z = blockIdx.z;
  in += (size_t)z * R * C;
  out += (size_t)z * R * C;
  const int tx = threadIdx.x & 63;
  const int ty = threadIdx.x >> 6;
  const int c0 = blockIdx.x * 64;
  const int r0 = blockIdx.y * 64;
#pragma unroll
  for (int it = 0; it < 16; ++it) {
    const int rr = ty * 16 + it;
    tile[rr][tx] = in[(size_t)(r0 + rr) * C + c0 + tx];
  }
  __syncthreads();
#pragma unroll
  for (int it = 0; it < 16; ++it) {
    const int rr = ty * 16 + it;
    out[(size_t)(c0 + rr) * R + r0 + tx] = tile[tx][rr];
  }
}

// ---------------- 128x128 bf16 GEMM (m97 structure) + XCD swizzle ----------------
// C[M][N] = A[M][K] * Bt[N][K]^T. 4 waves (2x2), 64x64/wave, BK=64, 32 KB LDS
// (~3-4 blocks/CU -> implicit wave-level stage/compute overlap, m114).
// COLMAJ=1: bm fastest within XCD chunk (each XCD owns B-columns; for N>>M).
// COLMAJ=0: bn fastest (each XCD owns A-rows; for M>>N).
template <int OUTF32, int COLMAJ>
__global__ __launch_bounds__(256, 2) void gemm_bt(const u16* __restrict__ A,
                                                  const u16* __restrict__ Bt,
                                                  void* __restrict__ Cvoid,
                                                  const float* __restrict__ bias, int N, int K,
                                                  int nb) {
  __shared__ u16 As[128 * 64];
  __shared__ u16 Bs[128 * 64];
  const int t = threadIdx.x;
  const int l = t & 63;
  const int w = t >> 6;
  const int lr = l & 15;
  const int lg = l >> 4;
  const int nwg = gridDim.x;
  const int cpx = nwg >> 3;
  const int swz = (blockIdx.x & 7) * cpx + (blockIdx.x >> 3);
  const int bm = COLMAJ ? (swz % nb) : (swz / nb);
  const int bn = COLMAJ ? (swz / nb) : (swz % nb);
  const int m0 = bm * 128;
  const int n0 = bn * 128;
  const int wm = (w >> 1) * 64;
  const int wn = (w & 1) * 64;

  f32x4 acc[4][4] = {};
  const int obase = w * 1024 + l * 16;  // byte offset within 16KB tile

  for (int k0 = 0; k0 < K; k0 += 64) {
#pragma unroll
    for (int rnd = 0; rnd < 4; ++rnd) {
      const int o = obase + rnd * 4096;
      const int row = o >> 7;          // 128 B per row
      const int g = (o & 127) >> 4;    // 16B granule within row
      const int gs = g ^ (row & 7);    // pre-swizzle the SOURCE
      gld16(A + (size_t)(m0 + row) * K + k0 + gs * 8, &As[rnd * 2048 + w * 512]);
      gld16(Bt + (size_t)(n0 + row) * K + k0 + gs * 8, &Bs[rnd * 2048 + w * 512]);
    }
    __syncthreads();

    bf16x8 af[4][2], bfr[4][2];
#pragma unroll
    for (int i = 0; i < 4; ++i) {
#pragma unroll
      for (int kc = 0; kc < 2; ++kc) {
        const int ra = wm + i * 16 + lr;
        af[i][kc] = *(const bf16x8*)&As[ra * 64 + (((kc * 4 + lg) ^ (ra & 7)) * 8)];
        const int rb = wn + i * 16 + lr;
        bfr[i][kc] = *(const bf16x8*)&Bs[rb * 64 + (((kc * 4 + lg) ^ (rb & 7)) * 8)];
      }
    }
#pragma unroll
    for (int kc = 0; kc < 2; ++kc)
#pragma unroll
      for (int i = 0; i < 4; ++i)
#pragma unroll
        for (int j = 0; j < 4; ++j)
          acc[i][j] = MFMA16(af[i][kc], bfr[j][kc], acc[i][j]);
    __syncthreads();
  }

  if (OUTF32) {
    float* C = (float*)Cvoid;
#pragma unroll
    for (int i = 0; i < 4; ++i)
#pragma unroll
      for (int j = 0; j < 4; ++j)
#pragma unroll
        for (int r = 0; r < 4; ++r) {
          const int row = m0 + wm + i * 16 + lg * 4 + r;
          const int col = n0 + wn + j * 16 + lr;
          C[(size_t)row * N + col] = acc[i][j][r] + bias[col];
        }
  } else {
    u16* C = (u16*)Cvoid;
#pragma unroll
    for (int i = 0; i < 4; ++i)
#pragma unroll
      for (int j = 0; j < 4; ++j)
#pragma unroll
        for (int r = 0; r < 4; ++r) {
          const int row = m0 + wm + i * 16 + lg * 4 + r;
          const int col = n0 + wn + j * 16 + lr;
          C[(size_t)row * N + col] = f2bf(acc[i][j][r]);
        }
  }
}

// ---------------- fused RMSNorm + RoPE + split to Q/K/V [bh][s][d] ----------------
__global__ __launch_bounds__(256) void norm_rope(const u16* __restrict__ proj,
                                                 const float* __restrict__ cosT,
                                                 const float* __restrict__ sinT,
                                                 const float* __restrict__ wq,
                                                 const float* __restrict__ wk,
                                                 u16* __restrict__ Qb, u16* __restrict__ Kb,
                                                 u16* __restrict__ Vb) {
  const int l = threadIdx.x & 63;
  const int wg = blockIdx.x * 4 + (threadIdx.x >> 6);
  const int h = wg & 15;
  const int r = wg >> 4;       // 0..4095
  const int b = r >> 11;       // /S
  const int s = r & 2047;
  const int bh = (b << 4) + h;

  const u16* p = proj + (size_t)r * NPROJ + h * 128 + 2 * l;
  const u32 qu = *(const u32*)(p);
  const u32 ku = *(const u32*)(p + QDIM);
  const u32 vu = *(const u32*)(p + 2 * QDIM);

  const float q0 = bf2f(qu & 0xffff), q1 = bf2f(qu >> 16);
  const float k0 = bf2f(ku & 0xffff), k1 = bf2f(ku >> 16);

  float sq = q0 * q0 + q1 * q1;
  float sk = k0 * k0 + k1 * k1;
#pragma unroll
  for (int m = 1; m < 64; m <<= 1) {
    sq += __shfl_xor(sq, m);
    sk += __shfl_xor(sk, m);
  }
  const float scq = rsqrtf(sq * (1.0f / 128.0f) + 1e-5f);
  const float sck = rsqrtf(sk * (1.0f / 128.0f) + 1e-5f);

  const float2 cc = *(const float2*)&cosT[s * 128 + 2 * l];
  const float2 ssn = *(const float2*)&sinT[s * 128 + 2 * l];
  const float w0 = wq[2 * l], w1 = wq[2 * l + 1];
  const float x0 = wk[2 * l], x1 = wk[2 * l + 1];

  const float qn0 = q0 * scq * w0, qn1 = q1 * scq * w1;
  const float kn0 = k0 * sck * x0, kn1 = k1 * sck * x1;

  const float ATT = 0.08838834764831845f;  // 128^-0.5 (pre-scale Q for attention)
  const float qr0 = (qn0 * cc.x - qn1 * ssn.x) * ATT;
  const float qr1 = (qn1 * cc.y + qn0 * ssn.y) * ATT;
  const float kr0 = kn0 * cc.x - kn1 * ssn.x;
  const float kr1 = kn1 * cc.y + kn0 * ssn.y;

  const size_t dst = ((size_t)bh * S_LEN + s) * 128 + 2 * l;
  *(u32*)(Qb + dst) = (u32)f2bf(qr0) | ((u32)f2bf(qr1) << 16);
  *(u32*)(Kb + dst) = (u32)f2bf(kr0) | ((u32)f2bf(kr1) << 16);
  *(u32*)(Vb + dst) = vu;  // plain copy (bf16 passthrough)
}

// ---------------- SwiGLU: silu(m1)*m2 -> Cat[:, 2048:10240] ----------------
__global__ __launch_bounds__(256) void swiglu(const u16* __restrict__ proj,
                                              u16* __restrict__ Cat) {
  const u32 i = blockIdx.x * 256 + threadIdx.x;  // quad index
  const u32 r = i >> 11;
  const u32 c = (i & 2047) * 4;
  const u16* p1 = proj + (size_t)r * NPROJ + 3 * QDIM + c;
  const uint2 a = *(const uint2*)p1;
  const uint2 bv = *(const uint2*)(p1 + 8192);
  const float a0 = bf2f(a.x & 0xffff), a1 = bf2f(a.x >> 16);
  const float a2 = bf2f(a.y & 0xffff), a3 = bf2f(a.y >> 16);
  const float b0 = bf2f(bv.x & 0xffff), b1 = bf2f(bv.x >> 16);
  const float b2 = bf2f(bv.y & 0xffff), b3 = bf2f(bv.y >> 16);
  const float o0 = a0 / (1.f + __expf(-a0)) * b0;
  const float o1 = a1 / (1.f + __expf(-a1)) * b1;
  const float o2 = a2 / (1.f + __expf(-a2)) * b2;
  const float o3 = a3 / (1.f + __expf(-a3)) * b3;
  uint2 o;
  o.x = (u32)f2bf(o0) | ((u32)f2bf(o1) << 16);
  o.y = (u32)f2bf(o2) | ((u32)f2bf(o3) << 16);
  *(uint2*)(Cat + (size_t)r * NCAT + QDIM + c) = o;
}

// ---------------- flash attention: 4 waves x 32 q-rows, KV tile = 64 ----------------
// Double-buffered K/V staging (T3 minimal 2-phase): stage kt+1 into buf^1
// BEFORE computing kt; single vmcnt(0)+barrier per tile. T5 setprio on MFMA.
// LDS: 2*16 + 2*16 + 16 = 80 KB -> 2 blocks/CU.
__global__ __launch_bounds__(256, 2) void attn_fwd(const u16* __restrict__ Qb,
                                                   const u16* __restrict__ Kb,
                                                   const u16* __restrict__ Vt,
                                                   u16* __restrict__ Cat) {
  __shared__ u16 Ks[2][64 * 128];   // [key][d], swz g^=key&7 (16 granules/row)
  __shared__ u16 Vs[2][128 * 64];   // [d][key], swz g^=d&7 (8 granules/row)
  __shared__ u16 Ps[4][32 * 64];    // per-wave P [q][key], swz g^=q&7

  const int t = threadIdx.x;
  const int l = t & 63;
  const int w = t >> 6;
  const int lr = l & 15;
  const int lg = l >> 4;
  const int qt = blockIdx.x;
  const int bh = blockIdx.y;
  const int b = bh >> 4;
  const int h = bh & 15;
  const int q0 = qt * 128 + w * 32;
  const int obase = w * 1024 + l * 16;

  const size_t kbase = (size_t)bh * S_LEN * 128;
  const size_t vbase = (size_t)bh * 128 * S_LEN;

  bf16x8 qf[2][4];
#pragma unroll
  for (int im = 0; im < 2; ++im)
#pragma unroll
    for (int kc = 0; kc < 4; ++kc)
      qf[im][kc] =
          *(const bf16x8*)&Qb[((size_t)bh * S_LEN + q0 + im * 16 + lr) * 128 + kc * 32 + lg * 8];

  f32x4 oacc[2][8] = {};
  float mrun[2][4], lrun[2][4];
#pragma unroll
  for (int im = 0; im < 2; ++im)
#pragma unroll
    for (int r = 0; r < 4; ++r) {
      mrun[im][r] = -1e30f;
      lrun[im][r] = 0.f;
    }

  u16* P = Ps[w];

  auto stageKV = [&](int buf, int kt2) {
    const int kk0 = kt2 * 64;
#pragma unroll
    for (int rnd = 0; rnd < 4; ++rnd) {
      const int o = obase + rnd * 4096;
      {
        const int key = o >> 8;
        const int g = (o & 255) >> 4;
        const int gs = g ^ (key & 7);
        gld16(Kb + kbase + (size_t)(kk0 + key) * 128 + gs * 8,
              &Ks[buf][rnd * 2048 + w * 512]);
      }
      {
        const int d = o >> 7;
        const int g = (o & 127) >> 4;
        const int gs = g ^ (d & 7);
        gld16(Vt + vbase + (size_t)d * S_LEN + kk0 + gs * 8,
              &Vs[buf][rnd * 2048 + w * 512]);
      }
    }
  };

  // prologue: stage tile 0
  stageKV(0, 0);
  WAITVM0();
  BARRIER();

  int cur = 0;
  for (int kt = 0; kt < 32; ++kt) {
    // issue next tile's staging first (targets buf^1 -> no WAR with compute)
    if (kt + 1 < 32) stageKV(cur ^ 1, kt + 1);

    const u16* Kc = &Ks[cur][0];
    const u16* Vc = &Vs[cur][0];

    // QK^T
    f32x4 sf[2][4] = {};
    __builtin_amdgcn_s_setprio(1);
#pragma unroll
    for (int j = 0; j < 4; ++j) {
      const int kr = j * 16 + lr;
      bf16x8 kf[4];
#pragma unroll
      for (int kc = 0; kc < 4; ++kc)
        kf[kc] = *(const bf16x8*)&Kc[kr * 128 + (((kc * 4 + lg) ^ (kr & 7)) * 8)];
#pragma unroll
      for (int kc = 0; kc < 4; ++kc)
#pragma unroll
        for (int im = 0; im < 2; ++im)
          sf[im][j] = MFMA16(qf[im][kc], kf[kc], sf[im][j]);
    }
    __builtin_amdgcn_s_setprio(0);

    // online softmax
#pragma unroll
    for (int im = 0; im < 2; ++im) {
#pragma unroll
      for (int r = 0; r < 4; ++r) {
        float v = fmaxf(fmaxf(sf[im][0][r], sf[im][1][r]), fmaxf(sf[im][2][r], sf[im][3][r]));
        v = fmaxf(v, __shfl_xor(v, 1));
        v = fmaxf(v, __shfl_xor(v, 2));
        v = fmaxf(v, __shfl_xor(v, 4));
        v = fmaxf(v, __shfl_xor(v, 8));
        const float mnew = fmaxf(mrun[im][r], v);
        const float alpha = __expf(mrun[im][r] - mnew);
        mrun[im][r] = mnew;
        float psum = 0.f;
#pragma unroll
        for (int j = 0; j < 4; ++j) {
          const float pv = __expf(sf[im][j][r] - mnew);
          sf[im][j][r] = pv;
          psum += pv;
        }
        psum += __shfl_xor(psum, 1);
        psum += __shfl_xor(psum, 2);
        psum += __shfl_xor(psum, 4);
        psum += __shfl_xor(psum, 8);
        lrun[im][r] = lrun[im][r] * alpha + psum;
#pragma unroll
        for (int df = 0; df < 8; ++df) oacc[im][df][r] *= alpha;
      }
    }

    // P -> per-wave LDS (swizzled for the A-frag read; same-wave RAW only)
#pragma unroll
    for (int im = 0; im < 2; ++im)
#pragma unroll
      for (int j = 0; j < 4; ++j)
#pragma unroll
        for (int r = 0; r < 4; ++r) {
          const int q = im * 16 + lg * 4 + r;
          const int key = j * 16 + lr;
          const int g = key >> 3;
          P[q * 64 + ((g ^ (q & 7)) * 8) + (key & 7)] = f2bf(sf[im][j][r]);
        }

    // PV
    __builtin_amdgcn_s_setprio(1);
#pragma unroll
    for (int kc = 0; kc < 2; ++kc) {
      bf16x8 pa[2];
#pragma unroll
      for (int im = 0; im < 2; ++im) {
        const int q = im * 16 + lr;
        pa[im] = *(const bf16x8*)&P[q * 64 + (((kc * 4 + lg) ^ (q & 7)) * 8)];
      }
#pragma unroll
      for (int df = 0; df < 8; ++df) {
        const int d = df * 16 + lr;
        const bf16x8 vb = *(const bf16x8*)&Vc[d * 64 + (((kc * 4 + lg) ^ (d & 7)) * 8)];
#pragma unroll
        for (int im = 0; im < 2; ++im) oacc[im][df] = MFMA16(pa[im], vb, oacc[im][df]);
      }
    }
    __builtin_amdgcn_s_setprio(0);

    // staged kt+1 visible to all waves before next iteration reads buf^1
    WAITVM0();
    BARRIER();
    cur ^= 1;
  }

  // epilogue
#pragma unroll
  for (int im = 0; im < 2; ++im)
#pragma unroll
    for (int r = 0; r < 4; ++r) {
      const float inv = 1.0f / lrun[im][r];
      const int row = b * S_LEN + q0 + im * 16 + lg * 4 + r;
#pragma unroll
      for (int df = 0; df < 8; ++df) {
        const int col = h * 128 + df * 16 + lr;
        Cat[(size_t)row * NCAT + col] = f2bf(oacc[im][df][r] * inv);
      }
    }
}

// ---------------- launch ----------------
extern "C" void kernel_launch(void* const* d_in, const int* in_sizes, int n_in, void* d_out,
                              int out_size, void* d_ws, size_t ws_size, hipStream_t stream) {
  (void)in_sizes; (void)n_in; (void)out_size; (void)ws_size;
  const float* hs = (const float*)d_in[0];
  const float* rcos = (const float*)d_in[1];
  const float* rsin = (const float*)d_in[2];
  const float* Wqkv = (const float*)d_in[3];
  const float* wq = (const float*)d_in[4];
  const float* wk = (const float*)d_in[5];
  const float* Wout = (const float*)d_in[6];
  const float* bout = (const float*)d_in[7];
  float* out = (float*)d_out;

  char* ws = (char*)d_ws;
  size_t off = 0;
  auto nxt = [&](size_t bytes) {
    char* p = ws + off;
    off += (bytes + 255) & ~(size_t)255;
    return p;
  };
  u16* Xb = (u16*)nxt((size_t)MROWS * QDIM * 2);
  u16* Wqkvt = (u16*)nxt((size_t)NPROJ * QDIM * 2);
  u16* Woutt = (u16*)nxt((size_t)QDIM * NCAT * 2);
  u16* proj = (u16*)nxt((size_t)MROWS * NPROJ * 2);
  u16* Qb = (u16*)nxt((size_t)NBH * S_LEN * D_HEAD * 2);
  u16* Kb = (u16*)nxt((size_t)NBH * S_LEN * D_HEAD * 2);
  u16* Vb = (u16*)nxt((size_t)NBH * S_LEN * D_HEAD * 2);
  u16* Vt = (u16*)nxt((size_t)NBH * S_LEN * D_HEAD * 2);
  u16* Cat = (u16*)nxt((size_t)MROWS * NCAT * 2);

  // 1) convert / transpose to bf16
  f32_to_bf16<<<(MROWS * QDIM / 4) / 256, 256, 0, stream>>>(hs, Xb);
  transpose_f32_bf16<<<dim3(NPROJ / 64, QDIM / 64), 256, 0, stream>>>(Wqkv, Wqkvt, QDIM, NPROJ);
  transpose_f32_bf16<<<dim3(QDIM / 64, NCAT / 64), 256, 0, stream>>>(Wout, Woutt, NCAT, QDIM);

  // 2) fused QKV+MLP projection — 128² m97 structure, col-major XCD chunks
  //    grid 32x176 = 5632 (div by 8); each XCD owns 22 B-column blocks.
  gemm_bt<0, 1><<<(MROWS / 128) * (NPROJ / 128), 256, 0, stream>>>(Xb, Wqkvt, proj, nullptr,
                                                                   NPROJ, QDIM, MROWS / 128);

  // 3) RMSNorm + RoPE + QKV split; V transpose
  norm_rope<<<MROWS * NHEADS / 4, 256, 0, stream>>>(proj, rcos, rsin, wq, wk, Qb, Kb, Vb);
  transpose_bf16_b<<<dim3(D_HEAD / 64, S_LEN / 64, NBH), 256, 0, stream>>>(Vb, Vt, S_LEN, D_HEAD);

  // 4) SwiGLU
  swiglu<<<(MROWS * 8192 / 4) / 256, 256, 0, stream>>>(proj, Cat);

  // 5) flash attention (double-buffered K/V)
  attn_fwd<<<dim3(S_LEN / 128, NBH), 256, 0, stream>>>(Qb, Kb, Vt, Cat);

  // 6) output projection + bias — 128², row-major XCD chunks (M>N here)
  gemm_bt<1, 0><<<(MROWS / 128) * (QDIM / 128), 256, 0, stream>>>(Cat, Woutt, out, bout, QDIM,
                                                                  NCAT, QDIM / 128);
}

// Round 5
// 816.619 us; speedup vs baseline: 1.2905x; 1.1433x over previous
//
#include <hip/hip_runtime.h>

typedef unsigned short u16;
typedef unsigned int u32;
typedef __bf16 bf16x8 __attribute__((ext_vector_type(8)));
typedef float f32x4 __attribute__((ext_vector_type(4)));

#define MFMA16(a, b, c) __builtin_amdgcn_mfma_f32_16x16x32_bf16((a), (b), (c), 0, 0, 0)

// ---- constants ----
#define S_LEN 2048
#define D_HEAD 128
#define NHEADS 16
#define NBH 32          // B*HEADS
#define QDIM 2048
#define NPROJ 22528     // 3*INNER + 2*MLP_HID
#define NQKV 6144       // 3*INNER
#define NMLP 16384      // 2*MLP_HID
#define NCAT 10240      // INNER + MLP_HID
#define MROWS 4096      // B*S

#define BARRIER() __builtin_amdgcn_s_barrier()
#define WAITVM0() asm volatile("s_waitcnt vmcnt(0)" ::: "memory")

__device__ __forceinline__ float bf2f(u16 u) { return __uint_as_float(((u32)u) << 16); }
__device__ __forceinline__ u16 f2bf(float f) {
  u32 u = __float_as_uint(f);
  return (u16)((u + 0x7FFFu + ((u >> 16) & 1u)) >> 16);
}
__device__ __forceinline__ void gld16(const void* g, void* l) {
  __builtin_amdgcn_global_load_lds((__attribute__((address_space(1))) void*)(g),
                                   (__attribute__((address_space(3))) void*)(l), 16, 0, 0);
}

// ---------------- f32 -> bf16 elementwise (vectorized) ----------------
__global__ __launch_bounds__(256) void f32_to_bf16(const float* __restrict__ in,
                                                   u16* __restrict__ out) {
  const u32 i = blockIdx.x * 256 + threadIdx.x;  // one float4 per thread
  const float4 v = ((const float4*)in)[i];
  uint2 o;
  o.x = (u32)f2bf(v.x) | ((u32)f2bf(v.y) << 16);
  o.y = (u32)f2bf(v.z) | ((u32)f2bf(v.w) << 16);
  ((uint2*)out)[i] = o;
}

// ---------------- tiled transpose-convert: in[R][C] f32 -> out[C][R] bf16 ----------------
// REMAP=1 (for W_qkv_mlp): output rows >= NQKV get the m1/m2 16-row interleave
// permutation row' = NQKV + ((f>>4)<<5 | sel<<4 | (f&15)), f=c&8191, sel=c>>13,
// so the fused-SwiGLU GEMM pairs m1/m2 as adjacent 16-row j-fragments.
template <int REMAP>
__global__ __launch_bounds__(256) void transpose_f32_bf16(const float* __restrict__ in,
                                                          u16* __restrict__ out, int R, int C) {
  __shared__ u16 tile[64][65];
  const int tx = threadIdx.x & 63;
  const int ty = threadIdx.x >> 6;
  const int c0 = blockIdx.x * 64;
  const int r0 = blockIdx.y * 64;
#pragma unroll
  for (int it = 0; it < 16; ++it) {
    const int rr = ty * 16 + it;
    tile[rr][tx] = f2bf(in[(size_t)(r0 + rr) * C + c0 + tx]);
  }
  __syncthreads();
#pragma unroll
  for (int it = 0; it < 16; ++it) {
    const int rr = ty * 16 + it;
    int orow = c0 + rr;
    if (REMAP && orow >= NQKV) {
      const int c = orow - NQKV;
      const int f = c & 8191;
      const int sel = c >> 13;
      orow = NQKV + (((f >> 4) << 5) | (sel << 4) | (f & 15));
    }
    out[(size_t)orow * R + r0 + tx] = tile[tx][rr];
  }
}

// ---------------- batched bf16 transpose: in[z][R][C] -> out[z][C][R] ----------------
__global__ __launch_bounds__(256) void transpose_bf16_b(const u16* __restrict__ in,
                                                        u16* __restrict__ out, int R, int C) {
  __shared__ u16 tile[64][65];
  const int z = blockIdx.z;
  in += (size_t)z * R * C;
  out += (size_t)z * R * C;
  const int tx = threadIdx.x & 63;
  const int ty = threadIdx.x >> 6;
  const int c0 = blockIdx.x * 64;
  const int r0 = blockIdx.y * 64;
#pragma unroll
  for (int it = 0; it < 16; ++it) {
    const int rr = ty * 16 + it;
    tile[rr][tx] = in[(size_t)(r0 + rr) * C + c0 + tx];
  }
  __syncthreads();
#pragma unroll
  for (int it = 0; it < 16; ++it) {
    const int rr = ty * 16 + it;
    out[(size_t)(c0 + rr) * R + r0 + tx] = tile[tx][rr];
  }
}

// ---------------- 128x128 bf16 GEMM (m97 structure, plain 2-D grid) ----------------
// C[M][N] = A[M][K] * Bt[N][K]^T. 4 waves (2x2), 64x64/wave, BK=64, 32 KB LDS.
// OUTMODE 0: bf16 store. 1: f32 + bias. 2: fused SwiGLU (B rows interleaved
// m1/m2 in 16-row groups; out col = (B-row)>>1, stride N, ptr pre-offset).
template <int OUTMODE>
__global__ __launch_bounds__(256, 2) void gemm_bt(const u16* __restrict__ A,
                                                  const u16* __restrict__ Bt,
                                                  void* __restrict__ Cvoid,
                                                  const float* __restrict__ bias, int N, int K) {
  __shared__ u16 As[128 * 64];
  __shared__ u16 Bs[128 * 64];
  const int t = threadIdx.x;
  const int l = t & 63;
  const int w = t >> 6;
  const int lr = l & 15;
  const int lg = l >> 4;
  const int m0 = blockIdx.y * 128;
  const int n0 = blockIdx.x * 128;
  const int wm = (w >> 1) * 64;
  const int wn = (w & 1) * 64;

  f32x4 acc[4][4] = {};
  const int obase = w * 1024 + l * 16;  // byte offset within 16KB tile

  for (int k0 = 0; k0 < K; k0 += 64) {
#pragma unroll
    for (int rnd = 0; rnd < 4; ++rnd) {
      const int o = obase + rnd * 4096;
      const int row = o >> 7;          // 128 B per row
      const int g = (o & 127) >> 4;    // 16B granule within row
      const int gs = g ^ (row & 7);    // pre-swizzle the SOURCE
      gld16(A + (size_t)(m0 + row) * K + k0 + gs * 8, &As[rnd * 2048 + w * 512]);
      gld16(Bt + (size_t)(n0 + row) * K + k0 + gs * 8, &Bs[rnd * 2048 + w * 512]);
    }
    __syncthreads();

    bf16x8 af[4][2], bfr[4][2];
#pragma unroll
    for (int i = 0; i < 4; ++i) {
#pragma unroll
      for (int kc = 0; kc < 2; ++kc) {
        const int ra = wm + i * 16 + lr;
        af[i][kc] = *(const bf16x8*)&As[ra * 64 + (((kc * 4 + lg) ^ (ra & 7)) * 8)];
        const int rb = wn + i * 16 + lr;
        bfr[i][kc] = *(const bf16x8*)&Bs[rb * 64 + (((kc * 4 + lg) ^ (rb & 7)) * 8)];
      }
    }
#pragma unroll
    for (int kc = 0; kc < 2; ++kc)
#pragma unroll
      for (int i = 0; i < 4; ++i)
#pragma unroll
        for (int j = 0; j < 4; ++j)
          acc[i][j] = MFMA16(af[i][kc], bfr[j][kc], acc[i][j]);
    __syncthreads();
  }

  if (OUTMODE == 1) {
    float* C = (float*)Cvoid;
#pragma unroll
    for (int i = 0; i < 4; ++i)
#pragma unroll
      for (int j = 0; j < 4; ++j)
#pragma unroll
        for (int r = 0; r < 4; ++r) {
          const int row = m0 + wm + i * 16 + lg * 4 + r;
          const int col = n0 + wn + j * 16 + lr;
          C[(size_t)row * N + col] = acc[i][j][r] + bias[col];
        }
  } else if (OUTMODE == 0) {
    u16* C = (u16*)Cvoid;
#pragma unroll
    for (int i = 0; i < 4; ++i)
#pragma unroll
      for (int j = 0; j < 4; ++j)
#pragma unroll
        for (int r = 0; r < 4; ++r) {
          const int row = m0 + wm + i * 16 + lg * 4 + r;
          const int col = n0 + wn + j * 16 + lr;
          C[(size_t)row * N + col] = f2bf(acc[i][j][r]);
        }
  } else {
    // fused SwiGLU: j=2jj holds m1, j=2jj+1 holds m2 (same lane, same cols)
    u16* C = (u16*)Cvoid;  // pre-offset to Cat + QDIM
#pragma unroll
    for (int i = 0; i < 4; ++i)
#pragma unroll
      for (int jj = 0; jj < 2; ++jj)
#pragma unroll
        for (int r = 0; r < 4; ++r) {
          const int row = m0 + wm + i * 16 + lg * 4 + r;
          const float a1 = acc[i][2 * jj][r];
          const float a2 = acc[i][2 * jj + 1][r];
          const float fz = a1 / (1.f + __expf(-a1)) * a2;
          const int col = ((n0 + wn) >> 1) + jj * 16 + lr;
          C[(size_t)row * N + col] = f2bf(fz);
        }
  }
}

// ---------------- fused RMSNorm + RoPE + split to Q/K/V [bh][s][d] ----------------
// proj is now [MROWS][NQKV] (qkv only).
__global__ __launch_bounds__(256) void norm_rope(const u16* __restrict__ proj,
                                                 const float* __restrict__ cosT,
                                                 const float* __restrict__ sinT,
                                                 const float* __restrict__ wq,
                                                 const float* __restrict__ wk,
                                                 u16* __restrict__ Qb, u16* __restrict__ Kb,
                                                 u16* __restrict__ Vb) {
  const int l = threadIdx.x & 63;
  const int wg = blockIdx.x * 4 + (threadIdx.x >> 6);
  const int h = wg & 15;
  const int r = wg >> 4;       // 0..4095
  const int b = r >> 11;       // /S
  const int s = r & 2047;
  const int bh = (b << 4) + h;

  const u16* p = proj + (size_t)r * NQKV + h * 128 + 2 * l;
  const u32 qu = *(const u32*)(p);
  const u32 ku = *(const u32*)(p + QDIM);
  const u32 vu = *(const u32*)(p + 2 * QDIM);

  const float q0 = bf2f(qu & 0xffff), q1 = bf2f(qu >> 16);
  const float k0 = bf2f(ku & 0xffff), k1 = bf2f(ku >> 16);

  float sq = q0 * q0 + q1 * q1;
  float sk = k0 * k0 + k1 * k1;
#pragma unroll
  for (int m = 1; m < 64; m <<= 1) {
    sq += __shfl_xor(sq, m);
    sk += __shfl_xor(sk, m);
  }
  const float scq = rsqrtf(sq * (1.0f / 128.0f) + 1e-5f);
  const float sck = rsqrtf(sk * (1.0f / 128.0f) + 1e-5f);

  const float2 cc = *(const float2*)&cosT[s * 128 + 2 * l];
  const float2 ssn = *(const float2*)&sinT[s * 128 + 2 * l];
  const float w0 = wq[2 * l], w1 = wq[2 * l + 1];
  const float x0 = wk[2 * l], x1 = wk[2 * l + 1];

  const float qn0 = q0 * scq * w0, qn1 = q1 * scq * w1;
  const float kn0 = k0 * sck * x0, kn1 = k1 * sck * x1;

  const float ATT = 0.08838834764831845f;  // 128^-0.5 (pre-scale Q for attention)
  const float qr0 = (qn0 * cc.x - qn1 * ssn.x) * ATT;
  const float qr1 = (qn1 * cc.y + qn0 * ssn.y) * ATT;
  const float kr0 = kn0 * cc.x - kn1 * ssn.x;
  const float kr1 = kn1 * cc.y + kn0 * ssn.y;

  const size_t dst = ((size_t)bh * S_LEN + s) * 128 + 2 * l;
  *(u32*)(Qb + dst) = (u32)f2bf(qr0) | ((u32)f2bf(qr1) << 16);
  *(u32*)(Kb + dst) = (u32)f2bf(kr0) | ((u32)f2bf(kr1) << 16);
  *(u32*)(Vb + dst) = vu;  // plain copy (bf16 passthrough)
}

// ---------------- flash attention: 4 waves x 32 q-rows, KV tile = 64 ----------------
// Double-buffered K/V staging + setprio on MFMA clusters. LDS 80 KB -> 2 blocks/CU.
__global__ __launch_bounds__(256, 2) void attn_fwd(const u16* __restrict__ Qb,
                                                   const u16* __restrict__ Kb,
                                                   const u16* __restrict__ Vt,
                                                   u16* __restrict__ Cat) {
  __shared__ u16 Ks[2][64 * 128];   // [key][d], swz g^=key&7 (16 granules/row)
  __shared__ u16 Vs[2][128 * 64];   // [d][key], swz g^=d&7 (8 granules/row)
  __shared__ u16 Ps[4][32 * 64];    // per-wave P [q][key], swz g^=q&7

  const int t = threadIdx.x;
  const int l = t & 63;
  const int w = t >> 6;
  const int lr = l & 15;
  const int lg = l >> 4;
  const int qt = blockIdx.x;
  const int bh = blockIdx.y;
  const int b = bh >> 4;
  const int h = bh & 15;
  const int q0 = qt * 128 + w * 32;
  const int obase = w * 1024 + l * 16;

  const size_t kbase = (size_t)bh * S_LEN * 128;
  const size_t vbase = (size_t)bh * 128 * S_LEN;

  bf16x8 qf[2][4];
#pragma unroll
  for (int im = 0; im < 2; ++im)
#pragma unroll
    for (int kc = 0; kc < 4; ++kc)
      qf[im][kc] =
          *(const bf16x8*)&Qb[((size_t)bh * S_LEN + q0 + im * 16 + lr) * 128 + kc * 32 + lg * 8];

  f32x4 oacc[2][8] = {};
  float mrun[2][4], lrun[2][4];
#pragma unroll
  for (int im = 0; im < 2; ++im)
#pragma unroll
    for (int r = 0; r < 4; ++r) {
      mrun[im][r] = -1e30f;
      lrun[im][r] = 0.f;
    }

  u16* P = Ps[w];

  auto stageKV = [&](int buf, int kt2) {
    const int kk0 = kt2 * 64;
#pragma unroll
    for (int rnd = 0; rnd < 4; ++rnd) {
      const int o = obase + rnd * 4096;
      {
        const int key = o >> 8;
        const int g = (o & 255) >> 4;
        const int gs = g ^ (key & 7);
        gld16(Kb + kbase + (size_t)(kk0 + key) * 128 + gs * 8,
              &Ks[buf][rnd * 2048 + w * 512]);
      }
      {
        const int d = o >> 7;
        const int g = (o & 127) >> 4;
        const int gs = g ^ (d & 7);
        gld16(Vt + vbase + (size_t)d * S_LEN + kk0 + gs * 8,
              &Vs[buf][rnd * 2048 + w * 512]);
      }
    }
  };

  // prologue: stage tile 0
  stageKV(0, 0);
  WAITVM0();
  BARRIER();

  int cur = 0;
  for (int kt = 0; kt < 32; ++kt) {
    if (kt + 1 < 32) stageKV(cur ^ 1, kt + 1);

    const u16* Kc = &Ks[cur][0];
    const u16* Vc = &Vs[cur][0];

    // QK^T
    f32x4 sf[2][4] = {};
    __builtin_amdgcn_s_setprio(1);
#pragma unroll
    for (int j = 0; j < 4; ++j) {
      const int kr = j * 16 + lr;
      bf16x8 kf[4];
#pragma unroll
      for (int kc = 0; kc < 4; ++kc)
        kf[kc] = *(const bf16x8*)&Kc[kr * 128 + (((kc * 4 + lg) ^ (kr & 7)) * 8)];
#pragma unroll
      for (int kc = 0; kc < 4; ++kc)
#pragma unroll
        for (int im = 0; im < 2; ++im)
          sf[im][j] = MFMA16(qf[im][kc], kf[kc], sf[im][j]);
    }
    __builtin_amdgcn_s_setprio(0);

    // online softmax
#pragma unroll
    for (int im = 0; im < 2; ++im) {
#pragma unroll
      for (int r = 0; r < 4; ++r) {
        float v = fmaxf(fmaxf(sf[im][0][r], sf[im][1][r]), fmaxf(sf[im][2][r], sf[im][3][r]));
        v = fmaxf(v, __shfl_xor(v, 1));
        v = fmaxf(v, __shfl_xor(v, 2));
        v = fmaxf(v, __shfl_xor(v, 4));
        v = fmaxf(v, __shfl_xor(v, 8));
        const float mnew = fmaxf(mrun[im][r], v);
        const float alpha = __expf(mrun[im][r] - mnew);
        mrun[im][r] = mnew;
        float psum = 0.f;
#pragma unroll
        for (int j = 0; j < 4; ++j) {
          const float pv = __expf(sf[im][j][r] - mnew);
          sf[im][j][r] = pv;
          psum += pv;
        }
        psum += __shfl_xor(psum, 1);
        psum += __shfl_xor(psum, 2);
        psum += __shfl_xor(psum, 4);
        psum += __shfl_xor(psum, 8);
        lrun[im][r] = lrun[im][r] * alpha + psum;
#pragma unroll
        for (int df = 0; df < 8; ++df) oacc[im][df][r] *= alpha;
      }
    }

    // P -> per-wave LDS (swizzled for the A-frag read; same-wave RAW only)
#pragma unroll
    for (int im = 0; im < 2; ++im)
#pragma unroll
      for (int j = 0; j < 4; ++j)
#pragma unroll
        for (int r = 0; r < 4; ++r) {
          const int q = im * 16 + lg * 4 + r;
          const int key = j * 16 + lr;
          const int g = key >> 3;
          P[q * 64 + ((g ^ (q & 7)) * 8) + (key & 7)] = f2bf(sf[im][j][r]);
        }

    // PV
    __builtin_amdgcn_s_setprio(1);
#pragma unroll
    for (int kc = 0; kc < 2; ++kc) {
      bf16x8 pa[2];
#pragma unroll
      for (int im = 0; im < 2; ++im) {
        const int q = im * 16 + lr;
        pa[im] = *(const bf16x8*)&P[q * 64 + (((kc * 4 + lg) ^ (q & 7)) * 8)];
      }
#pragma unroll
      for (int df = 0; df < 8; ++df) {
        const int d = df * 16 + lr;
        const bf16x8 vb = *(const bf16x8*)&Vc[d * 64 + (((kc * 4 + lg) ^ (d & 7)) * 8)];
#pragma unroll
        for (int im = 0; im < 2; ++im) oacc[im][df] = MFMA16(pa[im], vb, oacc[im][df]);
      }
    }
    __builtin_amdgcn_s_setprio(0);

    WAITVM0();
    BARRIER();
    cur ^= 1;
  }

  // epilogue
#pragma unroll
  for (int im = 0; im < 2; ++im)
#pragma unroll
    for (int r = 0; r < 4; ++r) {
      const float inv = 1.0f / lrun[im][r];
      const int row = b * S_LEN + q0 + im * 16 + lg * 4 + r;
#pragma unroll
      for (int df = 0; df < 8; ++df) {
        const int col = h * 128 + df * 16 + lr;
        Cat[(size_t)row * NCAT + col] = f2bf(oacc[im][df][r] * inv);
      }
    }
}

// ---------------- launch ----------------
extern "C" void kernel_launch(void* const* d_in, const int* in_sizes, int n_in, void* d_out,
                              int out_size, void* d_ws, size_t ws_size, hipStream_t stream) {
  (void)in_sizes; (void)n_in; (void)out_size; (void)ws_size;
  const float* hs = (const float*)d_in[0];
  const float* rcos = (const float*)d_in[1];
  const float* rsin = (const float*)d_in[2];
  const float* Wqkv = (const float*)d_in[3];
  const float* wq = (const float*)d_in[4];
  const float* wk = (const float*)d_in[5];
  const float* Wout = (const float*)d_in[6];
  const float* bout = (const float*)d_in[7];
  float* out = (float*)d_out;

  char* ws = (char*)d_ws;
  size_t off = 0;
  auto nxt = [&](size_t bytes) {
    char* p = ws + off;
    off += (bytes + 255) & ~(size_t)255;
    return p;
  };
  u16* Xb = (u16*)nxt((size_t)MROWS * QDIM * 2);          // 16.8 MB
  u16* Wqkvt = (u16*)nxt((size_t)NPROJ * QDIM * 2);       // 92.3 MB
  u16* Woutt = (u16*)nxt((size_t)QDIM * NCAT * 2);        // 41.9 MB
  u16* proj = (u16*)nxt((size_t)MROWS * NQKV * 2);        // 50.3 MB (qkv only)
  u16* Qb = (u16*)nxt((size_t)NBH * S_LEN * D_HEAD * 2);  // 16.8 MB
  u16* Kb = (u16*)nxt((size_t)NBH * S_LEN * D_HEAD * 2);
  u16* Vb = (u16*)nxt((size_t)NBH * S_LEN * D_HEAD * 2);
  u16* Vt = (u16*)nxt((size_t)NBH * S_LEN * D_HEAD * 2);
  u16* Cat = (u16*)nxt((size_t)MROWS * NCAT * 2);         // 83.9 MB

  // 1) convert / transpose to bf16 (Wqkv with MLP m1/m2 interleave remap)
  f32_to_bf16<<<(MROWS * QDIM / 4) / 256, 256, 0, stream>>>(hs, Xb);
  transpose_f32_bf16<1><<<dim3(NPROJ / 64, QDIM / 64), 256, 0, stream>>>(Wqkv, Wqkvt, QDIM,
                                                                         NPROJ);
  transpose_f32_bf16<0><<<dim3(QDIM / 64, NCAT / 64), 256, 0, stream>>>(Wout, Woutt, NCAT, QDIM);

  // 2a) QKV projection -> proj [4096][6144]
  gemm_bt<0><<<dim3(NQKV / 128, MROWS / 128), 256, 0, stream>>>(Xb, Wqkvt, proj, nullptr,
                                                                NQKV, QDIM);
  // 2b) MLP projection + fused SwiGLU -> Cat[:, 2048:10240]
  gemm_bt<2><<<dim3(NMLP / 128, MROWS / 128), 256, 0, stream>>>(
      Xb, Wqkvt + (size_t)NQKV * QDIM, Cat + QDIM, nullptr, NCAT, QDIM);

  // 3) RMSNorm + RoPE + QKV split; V transpose
  norm_rope<<<MROWS * NHEADS / 4, 256, 0, stream>>>(proj, rcos, rsin, wq, wk, Qb, Kb, Vb);
  transpose_bf16_b<<<dim3(D_HEAD / 64, S_LEN / 64, NBH), 256, 0, stream>>>(Vb, Vt, S_LEN, D_HEAD);

  // 4) flash attention -> Cat[:, 0:2048]
  attn_fwd<<<dim3(S_LEN / 128, NBH), 256, 0, stream>>>(Qb, Kb, Vt, Cat);

  // 5) output projection + bias (f32 out)
  gemm_bt<1><<<dim3(QDIM / 128, MROWS / 128), 256, 0, stream>>>(Cat, Woutt, out, bout, QDIM,
                                                                NCAT);
}

// Round 6
// 777.451 us; speedup vs baseline: 1.3555x; 1.0504x over previous
//
#include <hip/hip_runtime.h>

typedef unsigned short u16;
typedef unsigned int u32;
typedef __bf16 bf16x8 __attribute__((ext_vector_type(8)));
typedef float f32x4 __attribute__((ext_vector_type(4)));

#define MFMA16(a, b, c) __builtin_amdgcn_mfma_f32_16x16x32_bf16((a), (b), (c), 0, 0, 0)

// ---- constants ----
#define S_LEN 2048
#define D_HEAD 128
#define NHEADS 16
#define NBH 32          // B*HEADS
#define QDIM 2048
#define NPROJ 22528     // 3*INNER + 2*MLP_HID
#define NQKV 6144       // 3*INNER
#define NMLP 16384      // 2*MLP_HID
#define NCAT 10240      // INNER + MLP_HID
#define MROWS 4096      // B*S

#define BARRIER() __builtin_amdgcn_s_barrier()
#define WAITVM0() asm volatile("s_waitcnt vmcnt(0)" ::: "memory")

__device__ __forceinline__ float bf2f(u16 u) { return __uint_as_float(((u32)u) << 16); }
__device__ __forceinline__ u16 f2bf(float f) {
  u32 u = __float_as_uint(f);
  return (u16)((u + 0x7FFFu + ((u >> 16) & 1u)) >> 16);
}
__device__ __forceinline__ void gld16(const void* g, void* l) {
  __builtin_amdgcn_global_load_lds((__attribute__((address_space(1))) void*)(g),
                                   (__attribute__((address_space(3))) void*)(l), 16, 0, 0);
}

// ---------------- f32 -> bf16 elementwise (vectorized) ----------------
__global__ __launch_bounds__(256) void f32_to_bf16(const float* __restrict__ in,
                                                   u16* __restrict__ out) {
  const u32 i = blockIdx.x * 256 + threadIdx.x;  // one float4 per thread
  const float4 v = ((const float4*)in)[i];
  uint2 o;
  o.x = (u32)f2bf(v.x) | ((u32)f2bf(v.y) << 16);
  o.y = (u32)f2bf(v.z) | ((u32)f2bf(v.w) << 16);
  ((uint2*)out)[i] = o;
}

// ---------------- tiled transpose-convert: in[R][C] f32 -> out[C][R] bf16 ----------------
// REMAP=1 (for W_qkv_mlp): output rows >= NQKV get the m1/m2 16-row interleave
// permutation row' = NQKV + ((f>>4)<<5 | sel<<4 | (f&15)), f=c&8191, sel=c>>13,
// so the fused-SwiGLU GEMM pairs m1/m2 as adjacent 16-row j-fragments.
template <int REMAP>
__global__ __launch_bounds__(256) void transpose_f32_bf16(const float* __restrict__ in,
                                                          u16* __restrict__ out, int R, int C) {
  __shared__ u16 tile[64][65];
  const int tx = threadIdx.x & 63;
  const int ty = threadIdx.x >> 6;
  const int c0 = blockIdx.x * 64;
  const int r0 = blockIdx.y * 64;
#pragma unroll
  for (int it = 0; it < 16; ++it) {
    const int rr = ty * 16 + it;
    tile[rr][tx] = f2bf(in[(size_t)(r0 + rr) * C + c0 + tx]);
  }
  __syncthreads();
#pragma unroll
  for (int it = 0; it < 16; ++it) {
    const int rr = ty * 16 + it;
    int orow = c0 + rr;
    if (REMAP && orow >= NQKV) {
      const int c = orow - NQKV;
      const int f = c & 8191;
      const int sel = c >> 13;
      orow = NQKV + (((f >> 4) << 5) | (sel << 4) | (f & 15));
    }
    out[(size_t)orow * R + r0 + tx] = tile[tx][rr];
  }
}

// ---------------- batched bf16 transpose: in[z][R][C] -> out[z][C][R] ----------------
__global__ __launch_bounds__(256) void transpose_bf16_b(const u16* __restrict__ in,
                                                        u16* __restrict__ out, int R, int C) {
  __shared__ u16 tile[64][65];
  const int z = blockIdx.z;
  in += (size_t)z * R * C;
  out += (size_t)z * R * C;
  const int tx = threadIdx.x & 63;
  const int ty = threadIdx.x >> 6;
  const int c0 = blockIdx.x * 64;
  const int r0 = blockIdx.y * 64;
#pragma unroll
  for (int it = 0; it < 16; ++it) {
    const int rr = ty * 16 + it;
    tile[rr][tx] = in[(size_t)(r0 + rr) * C + c0 + tx];
  }
  __syncthreads();
#pragma unroll
  for (int it = 0; it < 16; ++it) {
    const int rr = ty * 16 + it;
    out[(size_t)(c0 + rr) * R + r0 + tx] = tile[tx][rr];
  }
}

// ---------------- 128x128 bf16 GEMM (m97 structure, plain 2-D grid) ----------------
// OUTMODE 0: bf16 store. 1: f32 + bias. 2: fused SwiGLU.
template <int OUTMODE>
__global__ __launch_bounds__(256, 2) void gemm_bt(const u16* __restrict__ A,
                                                  const u16* __restrict__ Bt,
                                                  void* __restrict__ Cvoid,
                                                  const float* __restrict__ bias, int N, int K) {
  __shared__ u16 As[128 * 64];
  __shared__ u16 Bs[128 * 64];
  const int t = threadIdx.x;
  const int l = t & 63;
  const int w = t >> 6;
  const int lr = l & 15;
  const int lg = l >> 4;
  const int m0 = blockIdx.y * 128;
  const int n0 = blockIdx.x * 128;
  const int wm = (w >> 1) * 64;
  const int wn = (w & 1) * 64;

  f32x4 acc[4][4] = {};
  const int obase = w * 1024 + l * 16;  // byte offset within 16KB tile

  for (int k0 = 0; k0 < K; k0 += 64) {
#pragma unroll
    for (int rnd = 0; rnd < 4; ++rnd) {
      const int o = obase + rnd * 4096;
      const int row = o >> 7;          // 128 B per row
      const int g = (o & 127) >> 4;    // 16B granule within row
      const int gs = g ^ (row & 7);    // pre-swizzle the SOURCE
      gld16(A + (size_t)(m0 + row) * K + k0 + gs * 8, &As[rnd * 2048 + w * 512]);
      gld16(Bt + (size_t)(n0 + row) * K + k0 + gs * 8, &Bs[rnd * 2048 + w * 512]);
    }
    __syncthreads();

    bf16x8 af[4][2], bfr[4][2];
#pragma unroll
    for (int i = 0; i < 4; ++i) {
#pragma unroll
      for (int kc = 0; kc < 2; ++kc) {
        const int ra = wm + i * 16 + lr;
        af[i][kc] = *(const bf16x8*)&As[ra * 64 + (((kc * 4 + lg) ^ (ra & 7)) * 8)];
        const int rb = wn + i * 16 + lr;
        bfr[i][kc] = *(const bf16x8*)&Bs[rb * 64 + (((kc * 4 + lg) ^ (rb & 7)) * 8)];
      }
    }
#pragma unroll
    for (int kc = 0; kc < 2; ++kc)
#pragma unroll
      for (int i = 0; i < 4; ++i)
#pragma unroll
        for (int j = 0; j < 4; ++j)
          acc[i][j] = MFMA16(af[i][kc], bfr[j][kc], acc[i][j]);
    __syncthreads();
  }

  if (OUTMODE == 1) {
    float* C = (float*)Cvoid;
#pragma unroll
    for (int i = 0; i < 4; ++i)
#pragma unroll
      for (int j = 0; j < 4; ++j)
#pragma unroll
        for (int r = 0; r < 4; ++r) {
          const int row = m0 + wm + i * 16 + lg * 4 + r;
          const int col = n0 + wn + j * 16 + lr;
          C[(size_t)row * N + col] = acc[i][j][r] + bias[col];
        }
  } else if (OUTMODE == 0) {
    u16* C = (u16*)Cvoid;
#pragma unroll
    for (int i = 0; i < 4; ++i)
#pragma unroll
      for (int j = 0; j < 4; ++j)
#pragma unroll
        for (int r = 0; r < 4; ++r) {
          const int row = m0 + wm + i * 16 + lg * 4 + r;
          const int col = n0 + wn + j * 16 + lr;
          C[(size_t)row * N + col] = f2bf(acc[i][j][r]);
        }
  } else {
    // fused SwiGLU: j=2jj holds m1, j=2jj+1 holds m2 (same lane, same cols)
    u16* C = (u16*)Cvoid;  // pre-offset to Cat + QDIM
#pragma unroll
    for (int i = 0; i < 4; ++i)
#pragma unroll
      for (int jj = 0; jj < 2; ++jj)
#pragma unroll
        for (int r = 0; r < 4; ++r) {
          const int row = m0 + wm + i * 16 + lg * 4 + r;
          const float a1 = acc[i][2 * jj][r];
          const float a2 = acc[i][2 * jj + 1][r];
          const float fz = a1 / (1.f + __expf(-a1)) * a2;
          const int col = ((n0 + wn) >> 1) + jj * 16 + lr;
          C[(size_t)row * N + col] = f2bf(fz);
        }
  }
}

// ------------- QKV GEMM with fused RMSNorm + RoPE epilogue -------------
// Same m97 K-loop. Each 128-col block = one head of one of Q/K/V.
// Epilogue: per-row sum-sq (4 shfl + 1KB LDS cross-wave combine), weight*rsqrt,
// RoPE pair exchange via shfl_xor(.,1) (partner col = adjacent lane), write
// straight to Qb/Kb/Vb in [bh][s][d] layout. Q pre-scaled by 128^-0.5.
__global__ __launch_bounds__(256, 2) void gemm_qkv(const u16* __restrict__ A,
                                                   const u16* __restrict__ Bt,
                                                   const float* __restrict__ cosT,
                                                   const float* __restrict__ sinT,
                                                   const float* __restrict__ wq,
                                                   const float* __restrict__ wk,
                                                   u16* __restrict__ Qb, u16* __restrict__ Kb,
                                                   u16* __restrict__ Vb, int K) {
  __shared__ u16 As[128 * 64];
  __shared__ u16 Bs[128 * 64];
  __shared__ float redbuf[2][128];
  const int t = threadIdx.x;
  const int l = t & 63;
  const int w = t >> 6;
  const int lr = l & 15;
  const int lg = l >> 4;
  const int m0 = blockIdx.y * 128;
  const int n0 = blockIdx.x * 128;
  const int wm = (w >> 1) * 64;
  const int wn = (w & 1) * 64;

  f32x4 acc[4][4] = {};
  const int obase = w * 1024 + l * 16;

  for (int k0 = 0; k0 < K; k0 += 64) {
#pragma unroll
    for (int rnd = 0; rnd < 4; ++rnd) {
      const int o = obase + rnd * 4096;
      const int row = o >> 7;
      const int g = (o & 127) >> 4;
      const int gs = g ^ (row & 7);
      gld16(A + (size_t)(m0 + row) * K + k0 + gs * 8, &As[rnd * 2048 + w * 512]);
      gld16(Bt + (size_t)(n0 + row) * K + k0 + gs * 8, &Bs[rnd * 2048 + w * 512]);
    }
    __syncthreads();

    bf16x8 af[4][2], bfr[4][2];
#pragma unroll
    for (int i = 0; i < 4; ++i) {
#pragma unroll
      for (int kc = 0; kc < 2; ++kc) {
        const int ra = wm + i * 16 + lr;
        af[i][kc] = *(const bf16x8*)&As[ra * 64 + (((kc * 4 + lg) ^ (ra & 7)) * 8)];
        const int rb = wn + i * 16 + lr;
        bfr[i][kc] = *(const bf16x8*)&Bs[rb * 64 + (((kc * 4 + lg) ^ (rb & 7)) * 8)];
      }
    }
#pragma unroll
    for (int kc = 0; kc < 2; ++kc)
#pragma unroll
      for (int i = 0; i < 4; ++i)
#pragma unroll
        for (int j = 0; j < 4; ++j)
          acc[i][j] = MFMA16(af[i][kc], bfr[j][kc], acc[i][j]);
    __syncthreads();
  }

  const int type = n0 >> 11;          // 0=Q, 1=K, 2=V
  const int h = (n0 >> 7) & 15;
  u16* dst = (type == 0) ? Qb : (type == 1) ? Kb : Vb;

  if (type == 2) {
#pragma unroll
    for (int i = 0; i < 4; ++i)
#pragma unroll
      for (int j = 0; j < 4; ++j)
#pragma unroll
        for (int r = 0; r < 4; ++r) {
          const int row = m0 + wm + i * 16 + lg * 4 + r;
          const int s = row & 2047, b = row >> 11;
          const int col = wn + j * 16 + lr;
          dst[((size_t)(b * 16 + h) * S_LEN + s) * 128 + col] = f2bf(acc[i][j][r]);
        }
    return;
  }

  // per-row sum of squares: reduce 4 cols/thread over 16 lanes, then across wn
  float ssum[4][4];
#pragma unroll
  for (int i = 0; i < 4; ++i)
#pragma unroll
    for (int r = 0; r < 4; ++r) {
      float p = acc[i][0][r] * acc[i][0][r] + acc[i][1][r] * acc[i][1][r] +
                acc[i][2][r] * acc[i][2][r] + acc[i][3][r] * acc[i][3][r];
      p += __shfl_xor(p, 1);
      p += __shfl_xor(p, 2);
      p += __shfl_xor(p, 4);
      p += __shfl_xor(p, 8);
      ssum[i][r] = p;
    }
  if (lr == 0) {
#pragma unroll
    for (int i = 0; i < 4; ++i)
#pragma unroll
      for (int r = 0; r < 4; ++r) redbuf[wn >> 6][wm + i * 16 + lg * 4 + r] = ssum[i][r];
  }
  __syncthreads();

  const float* wgt = type ? wk : wq;
  const float sc = type ? 1.0f : 0.08838834764831845f;  // Q pre-scale 128^-0.5
#pragma unroll
  for (int i = 0; i < 4; ++i)
#pragma unroll
    for (int r = 0; r < 4; ++r) {
      const int lrow = wm + i * 16 + lg * 4 + r;
      const float tot = redbuf[0][lrow] + redbuf[1][lrow];
      const float rsq = rsqrtf(tot * (1.0f / 128.0f) + 1e-5f) * sc;
      const int row = m0 + lrow;
      const int s = row & 2047, b = row >> 11;
      const size_t rbase = ((size_t)(b * 16 + h) * S_LEN + s) * 128;
#pragma unroll
      for (int j = 0; j < 4; ++j) {
        const int col = wn + j * 16 + lr;
        const float xn = acc[i][j][r] * rsq * wgt[col];
        const float pr = __shfl_xor(xn, 1);
        const float c = cosT[s * 128 + col];
        const float sn = sinT[s * 128 + col];
        const float val = (col & 1) ? (xn * c + pr * sn) : (xn * c - pr * sn);
        dst[rbase + col] = f2bf(val);
      }
    }
}

// ---------------- flash attention: 4 waves x 32 q-rows, KV tile = 64 ----------------
// No-max online softmax: scores are bounded (RMS-normed Q,K scaled by 128^-0.5,
// |s| <= 11.3 worst-case, exp safe in f32) -> p=exp(s) directly, no rescale.
// Double-buffered K/V staging + setprio on MFMA clusters. LDS 80 KB.
__global__ __launch_bounds__(256, 2) void attn_fwd(const u16* __restrict__ Qb,
                                                   const u16* __restrict__ Kb,
                                                   const u16* __restrict__ Vt,
                                                   u16* __restrict__ Cat) {
  __shared__ u16 Ks[2][64 * 128];   // [key][d], swz g^=key&7 (16 granules/row)
  __shared__ u16 Vs[2][128 * 64];   // [d][key], swz g^=d&7 (8 granules/row)
  __shared__ u16 Ps[4][32 * 64];    // per-wave P [q][key], swz g^=q&7

  const int t = threadIdx.x;
  const int l = t & 63;
  const int w = t >> 6;
  const int lr = l & 15;
  const int lg = l >> 4;
  const int qt = blockIdx.x;
  const int bh = blockIdx.y;
  const int b = bh >> 4;
  const int h = bh & 15;
  const int q0 = qt * 128 + w * 32;
  const int obase = w * 1024 + l * 16;

  const size_t kbase = (size_t)bh * S_LEN * 128;
  const size_t vbase = (size_t)bh * 128 * S_LEN;

  bf16x8 qf[2][4];
#pragma unroll
  for (int im = 0; im < 2; ++im)
#pragma unroll
    for (int kc = 0; kc < 4; ++kc)
      qf[im][kc] =
          *(const bf16x8*)&Qb[((size_t)bh * S_LEN + q0 + im * 16 + lr) * 128 + kc * 32 + lg * 8];

  f32x4 oacc[2][8] = {};
  float lrun[2][4] = {};

  u16* P = Ps[w];

  auto stageKV = [&](int buf, int kt2) {
    const int kk0 = kt2 * 64;
#pragma unroll
    for (int rnd = 0; rnd < 4; ++rnd) {
      const int o = obase + rnd * 4096;
      {
        const int key = o >> 8;
        const int g = (o & 255) >> 4;
        const int gs = g ^ (key & 7);
        gld16(Kb + kbase + (size_t)(kk0 + key) * 128 + gs * 8,
              &Ks[buf][rnd * 2048 + w * 512]);
      }
      {
        const int d = o >> 7;
        const int g = (o & 127) >> 4;
        const int gs = g ^ (d & 7);
        gld16(Vt + vbase + (size_t)d * S_LEN + kk0 + gs * 8,
              &Vs[buf][rnd * 2048 + w * 512]);
      }
    }
  };

  // prologue: stage tile 0
  stageKV(0, 0);
  WAITVM0();
  BARRIER();

  int cur = 0;
  for (int kt = 0; kt < 32; ++kt) {
    if (kt + 1 < 32) stageKV(cur ^ 1, kt + 1);

    const u16* Kc = &Ks[cur][0];
    const u16* Vc = &Vs[cur][0];

    // QK^T
    f32x4 sf[2][4] = {};
    __builtin_amdgcn_s_setprio(1);
#pragma unroll
    for (int j = 0; j < 4; ++j) {
      const int kr = j * 16 + lr;
      bf16x8 kf[4];
#pragma unroll
      for (int kc = 0; kc < 4; ++kc)
        kf[kc] = *(const bf16x8*)&Kc[kr * 128 + (((kc * 4 + lg) ^ (kr & 7)) * 8)];
#pragma unroll
      for (int kc = 0; kc < 4; ++kc)
#pragma unroll
        for (int im = 0; im < 2; ++im)
          sf[im][j] = MFMA16(qf[im][kc], kf[kc], sf[im][j]);
    }
    __builtin_amdgcn_s_setprio(0);

    // no-max softmax: p = exp(s); row-sum reduce only
#pragma unroll
    for (int im = 0; im < 2; ++im) {
#pragma unroll
      for (int r = 0; r < 4; ++r) {
        float psum = 0.f;
#pragma unroll
        for (int j = 0; j < 4; ++j) {
          const float pv = __expf(sf[im][j][r]);
          sf[im][j][r] = pv;
          psum += pv;
        }
        psum += __shfl_xor(psum, 1);
        psum += __shfl_xor(psum, 2);
        psum += __shfl_xor(psum, 4);
        psum += __shfl_xor(psum, 8);
        lrun[im][r] += psum;
      }
    }

    // P -> per-wave LDS (swizzled for the A-frag read; same-wave RAW only)
#pragma unroll
    for (int im = 0; im < 2; ++im)
#pragma unroll
      for (int j = 0; j < 4; ++j)
#pragma unroll
        for (int r = 0; r < 4; ++r) {
          const int q = im * 16 + lg * 4 + r;
          const int key = j * 16 + lr;
          const int g = key >> 3;
          P[q * 64 + ((g ^ (q & 7)) * 8) + (key & 7)] = f2bf(sf[im][j][r]);
        }

    // PV
    __builtin_amdgcn_s_setprio(1);
#pragma unroll
    for (int kc = 0; kc < 2; ++kc) {
      bf16x8 pa[2];
#pragma unroll
      for (int im = 0; im < 2; ++im) {
        const int q = im * 16 + lr;
        pa[im] = *(const bf16x8*)&P[q * 64 + (((kc * 4 + lg) ^ (q & 7)) * 8)];
      }
#pragma unroll
      for (int df = 0; df < 8; ++df) {
        const int d = df * 16 + lr;
        const bf16x8 vb = *(const bf16x8*)&Vc[d * 64 + (((kc * 4 + lg) ^ (d & 7)) * 8)];
#pragma unroll
        for (int im = 0; im < 2; ++im) oacc[im][df] = MFMA16(pa[im], vb, oacc[im][df]);
      }
    }
    __builtin_amdgcn_s_setprio(0);

    WAITVM0();
    BARRIER();
    cur ^= 1;
  }

  // epilogue
#pragma unroll
  for (int im = 0; im < 2; ++im)
#pragma unroll
    for (int r = 0; r < 4; ++r) {
      const float inv = 1.0f / lrun[im][r];
      const int row = b * S_LEN + q0 + im * 16 + lg * 4 + r;
#pragma unroll
      for (int df = 0; df < 8; ++df) {
        const int col = h * 128 + df * 16 + lr;
        Cat[(size_t)row * NCAT + col] = f2bf(oacc[im][df][r] * inv);
      }
    }
}

// ---------------- launch ----------------
extern "C" void kernel_launch(void* const* d_in, const int* in_sizes, int n_in, void* d_out,
                              int out_size, void* d_ws, size_t ws_size, hipStream_t stream) {
  (void)in_sizes; (void)n_in; (void)out_size; (void)ws_size;
  const float* hs = (const float*)d_in[0];
  const float* rcos = (const float*)d_in[1];
  const float* rsin = (const float*)d_in[2];
  const float* Wqkv = (const float*)d_in[3];
  const float* wq = (const float*)d_in[4];
  const float* wk = (const float*)d_in[5];
  const float* Wout = (const float*)d_in[6];
  const float* bout = (const float*)d_in[7];
  float* out = (float*)d_out;

  char* ws = (char*)d_ws;
  size_t off = 0;
  auto nxt = [&](size_t bytes) {
    char* p = ws + off;
    off += (bytes + 255) & ~(size_t)255;
    return p;
  };
  u16* Xb = (u16*)nxt((size_t)MROWS * QDIM * 2);          // 16.8 MB
  u16* Wqkvt = (u16*)nxt((size_t)NPROJ * QDIM * 2);       // 92.3 MB
  u16* Woutt = (u16*)nxt((size_t)QDIM * NCAT * 2);        // 41.9 MB
  u16* Qb = (u16*)nxt((size_t)NBH * S_LEN * D_HEAD * 2);  // 16.8 MB
  u16* Kb = (u16*)nxt((size_t)NBH * S_LEN * D_HEAD * 2);
  u16* Vb = (u16*)nxt((size_t)NBH * S_LEN * D_HEAD * 2);
  u16* Vt = (u16*)nxt((size_t)NBH * S_LEN * D_HEAD * 2);
  u16* Cat = (u16*)nxt((size_t)MROWS * NCAT * 2);         // 83.9 MB

  // 1) convert / transpose to bf16 (Wqkv with MLP m1/m2 interleave remap)
  f32_to_bf16<<<(MROWS * QDIM / 4) / 256, 256, 0, stream>>>(hs, Xb);
  transpose_f32_bf16<1><<<dim3(NPROJ / 64, QDIM / 64), 256, 0, stream>>>(Wqkv, Wqkvt, QDIM,
                                                                         NPROJ);
  transpose_f32_bf16<0><<<dim3(QDIM / 64, NCAT / 64), 256, 0, stream>>>(Wout, Woutt, NCAT, QDIM);

  // 2a) QKV projection + fused RMSNorm/RoPE -> Qb/Kb/Vb directly
  gemm_qkv<<<dim3(NQKV / 128, MROWS / 128), 256, 0, stream>>>(Xb, Wqkvt, rcos, rsin, wq, wk,
                                                              Qb, Kb, Vb, QDIM);
  // 2b) MLP projection + fused SwiGLU -> Cat[:, 2048:10240]
  gemm_bt<2><<<dim3(NMLP / 128, MROWS / 128), 256, 0, stream>>>(
      Xb, Wqkvt + (size_t)NQKV * QDIM, Cat + QDIM, nullptr, NCAT, QDIM);

  // 3) V transpose for PV reads
  transpose_bf16_b<<<dim3(D_HEAD / 64, S_LEN / 64, NBH), 256, 0, stream>>>(Vb, Vt, S_LEN, D_HEAD);

  // 4) flash attention -> Cat[:, 0:2048]
  attn_fwd<<<dim3(S_LEN / 128, NBH), 256, 0, stream>>>(Qb, Kb, Vt, Cat);

  // 5) output projection + bias (f32 out)
  gemm_bt<1><<<dim3(QDIM / 128, MROWS / 128), 256, 0, stream>>>(Cat, Woutt, out, bout, QDIM,
                                                                NCAT);
}